// Round 2
// baseline (274.911 us; speedup 1.0000x reference)
//
#include <hip/hip_runtime.h>

// ---------------------------------------------------------------------------
// TemporalDifferentModuleMSDeformAttnVIZ — MI355X (gfx950)
// Round 12 = Round 11 resubmit (R11 bench was an infra failure: "container
// failed twice"; no counters returned. Source audit found no OOB / fault
// path; diff vs R10 is sampler de-VALU-ification, gated on ws_size).
// R10 counters: sampler 89.5us, VALUBusy 76%, HBM 9.4%, MFMA 0 ->
// VALU-issue-bound. Removed from the sampler instruction stream:
// (a) per-thread vote_f32 (~80 VALU x 4.18M threads), (b) bf16 unpack in
// the gather loop (4 shl + 4 and per corner), (c) dtype branches.
// Mechanism: gemmVP stores value as f32 head-major [NH][16320][32] (L3-
// resident, 16.7MB); prep kernel converts refp/toff to f32 once. Gather is
// now: 1 addr op + 2 float4 loads + 8 FMA per corner. bf16-value fallback
// path kept (template<VF32>) gated on ws_size >= 44.0MB.
// Constants: D=256 NH=8 DH=32 L=4 NCP=4 TW=2 NTP=2 P=8
// Levels (T*H, W): TH={192,96,48,24} W={64,32,16,8} starts={0,12288,15360,16128}
// Lq=16320
// ---------------------------------------------------------------------------

typedef unsigned short bfraw;
typedef __attribute__((ext_vector_type(4))) float f32x4;
typedef __attribute__((ext_vector_type(8))) short bf16x8;

__device__ __forceinline__ float bf2f(bfraw u) {
  union { unsigned int i; float f; } v; v.i = ((unsigned int)u) << 16; return v.f;
}
__device__ __forceinline__ bfraw f2bf(float f) {
  union { float f; unsigned int i; } v; v.f = f;
  unsigned int x = v.i;
  return (bfraw)((x + 0x7FFFu + ((x >> 16) & 1u)) >> 16);  // RNE
}
__device__ __forceinline__ float lo16f(unsigned int w) {
  union { unsigned int i; float f; } v; v.i = w << 16; return v.f;
}
__device__ __forceinline__ float hi16f(unsigned int w) {
  union { unsigned int i; float f; } v; v.i = w & 0xFFFF0000u; return v.f;
}
__device__ __forceinline__ float loadx(const void* p, size_t i, int f32m) {
  if (f32m) return ((const float*)p)[i];
  else      return bf2f(((const bfraw*)p)[i]);
}
__device__ __forceinline__ unsigned pk2(float a, float b) {
  return (unsigned)f2bf(a) | ((unsigned)f2bf(b) << 16);
}

// Uniform dtype vote from the first 64 B of `query`. bf16 data: low half of
// each dword is ~N(0,1), |x| in [1e-3,16) w.p. ~0.9985 -> cnt~16. f32 data:
// low halves are mantissa bits -> ~5% in range -> cnt~1. Returns 1 = f32.
__device__ __forceinline__ int vote_f32(const void* q) {
  const unsigned* p = (const unsigned*)q;
  int cnt = 0;
#pragma unroll
  for (int i = 0; i < 16; ++i) {
    const float a = fabsf(lo16f(p[i]));
    cnt += (a > 0.0009765625f && a < 16.0f) ? 1 : 0;
  }
  return (cnt >= 8) ? 0 : 1;
}

// Prep: transposed bf16 weights + bias concat + (f32 path) refp/toff -> f32.
// WT rows 0..255 = W_v^T ; 256..1023 = Wproj^T (so|tso|aw|taw col order);
// 1024..1279 = W_o^T. Blocks 1280..1282: bcat[768] f32 = b_so|b_tso|b_aw|b_taw.
// Blocks 1283..1792: refpF (130560 f32). Blocks 1793..2812: toffF (261120 f32).
// (Fallback path launches only 1283 blocks; refpF/toffF untouched.)
__global__ __launch_bounds__(256) void prep_k(
    const void* W_v, const void* W_so, const void* W_tso,
    const void* W_aw, const void* W_taw, const void* W_o,
    const void* b_so, const void* b_tso, const void* b_aw, const void* b_taw,
    const void* refp, const void* toff,
    bfraw* __restrict__ WT, float* __restrict__ bcat,
    float* __restrict__ refpF, float* __restrict__ toffF, const void* query)
{
  const int f32m = vote_f32(query);
  const int b = blockIdx.x, t = threadIdx.x;
  if (b < 1280) {
    float s;
    if (b < 256)       s = loadx(W_v, (size_t)t * 256 + b, f32m);
    else if (b < 1024) {
      const int rp = b - 256;
      if (rp < 256)      s = loadx(W_so,  (size_t)t * 256 + rp, f32m);
      else if (rp < 512) s = loadx(W_tso, (size_t)t * 256 + (rp - 256), f32m);
      else if (rp < 640) s = loadx(W_aw,  (size_t)t * 128 + (rp - 512), f32m);
      else               s = loadx(W_taw, (size_t)t * 128 + (rp - 640), f32m);
    } else               s = loadx(W_o,  (size_t)t * 256 + (b - 1024), f32m);
    WT[(size_t)b * 256 + t] = f2bf(s);
  } else if (b < 1283) {
    const int i = (b - 1280) * 256 + t;
    if (i < 768) {
      float s;
      if (i < 256)      s = loadx(b_so,  i, f32m);
      else if (i < 512) s = loadx(b_tso, i - 256, f32m);
      else if (i < 640) s = loadx(b_aw,  i - 512, f32m);
      else              s = loadx(b_taw, i - 640, f32m);
      bcat[i] = s;
    }
  } else if (b < 1793) {
    const int i = (b - 1283) * 256 + t;   // 510*256 == 130560 exactly
    refpF[i] = loadx(refp, i, f32m);
  } else {
    const int i = (b - 1793) * 256 + t;   // 1020*256 == 261120 exactly
    toffF[i] = loadx(toff, i, f32m);
  }
}

// Fused value + proj GEMM. 128x128 tiles, K=256, M=16320 (tail-guarded).
// blockIdx.y 0..1: value = inflat @ WvT^T + b_v
//   vf32=1 -> f32 head-major [NH][M][32]; vf32=0 -> bf16 [M][256]
// blockIdx.y 2..7: proj  = query @ WprojT^T + bcat -> bf16, ldc 768
__global__ __launch_bounds__(256) void gemmVP_k(
    const void* __restrict__ inflat, const void* __restrict__ query,
    const bfraw* __restrict__ WT, const void* __restrict__ b_v,
    const float* __restrict__ bcat,
    void* __restrict__ valueOut, bfraw* __restrict__ proj, int M, int vf32)
{
  __shared__ bfraw As[128][40];   // [m][k], +8 pad
  __shared__ bfraw Bs[128][40];   // [n][k]
  const int f32m = vote_f32(query);
  const int y = blockIdx.y;
  const void* A; int wtb, colb, bmode;
  if (y < 2) { A = inflat; wtb = y * 128;             colb = y * 128;       bmode = 1; }
  else       { A = query;  wtb = 256 + (y - 2) * 128; colb = (y - 2) * 128; bmode = 0; }

  const int bm = blockIdx.x * 128;
  const int tid = threadIdx.x;
  const int wave = tid >> 6, lane = tid & 63;
  const int quad = lane >> 4, l16 = lane & 15;
  const int mb = (wave >> 1) * 64, nb = (wave & 1) * 64;
  const int srow = tid >> 1;
  const int sk = (tid & 1) * 16;

  int lr = bm + srow; if (lr >= M) lr = M - 1;
  const size_t aoff = (size_t)lr * 256;

  f32x4 acc[4][4] = {{{0.f}}};

  for (int k0 = 0; k0 < 256; k0 += 32) {
    uint4 pa0, pa1;
    if (f32m) {
      const float* Af = (const float*)A + aoff + (k0 + sk);
      const float4 x0 = ((const float4*)Af)[0];
      const float4 x1 = ((const float4*)Af)[1];
      const float4 x2 = ((const float4*)Af)[2];
      const float4 x3 = ((const float4*)Af)[3];
      pa0.x = pk2(x0.x, x0.y); pa0.y = pk2(x0.z, x0.w);
      pa0.z = pk2(x1.x, x1.y); pa0.w = pk2(x1.z, x1.w);
      pa1.x = pk2(x2.x, x2.y); pa1.y = pk2(x2.z, x2.w);
      pa1.z = pk2(x3.x, x3.y); pa1.w = pk2(x3.z, x3.w);
    } else {
      const bfraw* Ab = (const bfraw*)A + aoff + (k0 + sk);
      pa0 = ((const uint4*)Ab)[0];
      pa1 = ((const uint4*)Ab)[1];
    }
    const bfraw* Bb = WT + (size_t)(wtb + srow) * 256 + (k0 + sk);
    const uint4 pb0 = ((const uint4*)Bb)[0];
    const uint4 pb1 = ((const uint4*)Bb)[1];
    *(uint4*)&As[srow][sk]     = pa0;
    *(uint4*)&As[srow][sk + 8] = pa1;
    *(uint4*)&Bs[srow][sk]     = pb0;
    *(uint4*)&Bs[srow][sk + 8] = pb1;
    __syncthreads();

    bf16x8 af[4], bf[4];
#pragma unroll
    for (int i = 0; i < 4; ++i)
      af[i] = *(const bf16x8*)&As[mb + i * 16 + l16][quad * 8];
#pragma unroll
    for (int j = 0; j < 4; ++j)
      bf[j] = *(const bf16x8*)&Bs[nb + j * 16 + l16][quad * 8];
#pragma unroll
    for (int i = 0; i < 4; ++i)
#pragma unroll
      for (int j = 0; j < 4; ++j)
        acc[i][j] = __builtin_amdgcn_mfma_f32_16x16x32_bf16(af[i], bf[j], acc[i][j], 0, 0, 0);
    __syncthreads();
  }

#pragma unroll
  for (int j = 0; j < 4; ++j) {
    const int col = colb + nb + j * 16 + l16;
    const float bb = bmode ? loadx(b_v, col, f32m) : bcat[col];
#pragma unroll
    for (int i = 0; i < 4; ++i) {
#pragma unroll
      for (int r = 0; r < 4; ++r) {
        const int lrow = bm + mb + i * 16 + quad * 4 + r;
        if (lrow < M) {
          const float vv = acc[i][j][r] + bb;
          if (!bmode)
            proj[(size_t)lrow * 768 + col] = f2bf(vv);
          else if (vf32)
            ((float*)valueOut)[((size_t)(col >> 5) * M + lrow) * 32 + (col & 31)] = vv;
          else
            ((bfraw*)valueOut)[(size_t)lrow * 256 + col] = f2bf(vv);
        }
      }
    }
  }
}

// O-projection GEMM: out[0..M) = core @ W_o + b_o; core = proj rows cols[0,256)
// (bf16, stride 768, written by sampler overlay). C dtype per vote.
__global__ __launch_bounds__(256) void gemmO_k(
    const bfraw* __restrict__ proj, const bfraw* __restrict__ WT,
    const void* __restrict__ b_o, void* __restrict__ Cout,
    const void* __restrict__ query, int M)
{
  __shared__ bfraw As[128][40];
  __shared__ bfraw Bs[128][40];
  const int f32m = vote_f32(query);
  const int bm = blockIdx.x * 128;
  const int bn = blockIdx.y * 128;
  const int tid = threadIdx.x;
  const int wave = tid >> 6, lane = tid & 63;
  const int quad = lane >> 4, l16 = lane & 15;
  const int mb = (wave >> 1) * 64, nb = (wave & 1) * 64;
  const int srow = tid >> 1;
  const int sk = (tid & 1) * 16;

  int lr = bm + srow; if (lr >= M) lr = M - 1;
  const size_t aoff = (size_t)lr * 768;

  f32x4 acc[4][4] = {{{0.f}}};

  for (int k0 = 0; k0 < 256; k0 += 32) {
    const bfraw* Ab = proj + aoff + (k0 + sk);
    const uint4 pa0 = ((const uint4*)Ab)[0];
    const uint4 pa1 = ((const uint4*)Ab)[1];
    const bfraw* Bb = WT + (size_t)(1024 + bn + srow) * 256 + (k0 + sk);
    const uint4 pb0 = ((const uint4*)Bb)[0];
    const uint4 pb1 = ((const uint4*)Bb)[1];
    *(uint4*)&As[srow][sk]     = pa0;
    *(uint4*)&As[srow][sk + 8] = pa1;
    *(uint4*)&Bs[srow][sk]     = pb0;
    *(uint4*)&Bs[srow][sk + 8] = pb1;
    __syncthreads();

    bf16x8 af[4], bf[4];
#pragma unroll
    for (int i = 0; i < 4; ++i)
      af[i] = *(const bf16x8*)&As[mb + i * 16 + l16][quad * 8];
#pragma unroll
    for (int j = 0; j < 4; ++j)
      bf[j] = *(const bf16x8*)&Bs[nb + j * 16 + l16][quad * 8];
#pragma unroll
    for (int i = 0; i < 4; ++i)
#pragma unroll
      for (int j = 0; j < 4; ++j)
        acc[i][j] = __builtin_amdgcn_mfma_f32_16x16x32_bf16(af[i], bf[j], acc[i][j], 0, 0, 0);
    __syncthreads();
  }

#pragma unroll
  for (int j = 0; j < 4; ++j) {
    const int col = bn + nb + j * 16 + l16;
    const float bb = loadx(b_o, col, f32m);
#pragma unroll
    for (int i = 0; i < 4; ++i) {
#pragma unroll
      for (int r = 0; r < 4; ++r) {
        const int lrow = bm + mb + i * 16 + quad * 4 + r;
        if (lrow < M) {
          const float v = acc[i][j][r] + bb;
          if (f32m) ((float*)Cout)[(size_t)lrow * 256 + col] = v;
          else      ((bfraw*)Cout)[(size_t)lrow * 256 + col] = f2bf(v);
        }
      }
    }
  }
}

// Sampler, head-major: grid (2040, 8); block = 8 queries x head blockIdx.y.
// VF32=1: value is f32 head-major [NH][16320][32] (slice 2.09MB, L2/L3-fit);
//         refp/toff are pre-converted f32 -> no vote, no dtype branches,
//         no bf16 unpack in the gather loop.
// VF32=0: legacy bf16 [16320][256] value + raw refp/toff (per-thread vote).
// proj row (768 bf16): [0,256) cso | [256,512) tso | [512,640) caw |
// [640,768) taw. Writes core slice (bf16, 32ch) over prow[h*32 .. h*32+32).
template<int VF32>
__global__ __launch_bounds__(256, 4) void sampler_k(
    bfraw* __restrict__ proj, const void* __restrict__ value,
    const void* __restrict__ refp, const void* __restrict__ toff,
    const void* __restrict__ query)
{
  __shared__ int   s_idx[256][4];  // clamped pixel index (always valid)
  __shared__ float s_w[256][4];    // attn*bilinear, 0 if OOB

  int f32m = 0;
  if constexpr (!VF32) f32m = vote_f32(query);
  const int h = blockIdx.y;
  const int tid = threadIdx.x;
  const int qi = tid >> 5;         // query-in-block 0..7
  const int sp = tid & 31;         // point-in-head
  const int l = sp >> 3;           // level
  const int p = sp & 7;            // 0..3 current, 4..7 temporal
  const int qg = blockIdx.x * 8 + qi;

  const int W_i[4]  = {64, 32, 16, 8};
  const int TH_i[4] = {192, 96, 48, 24};
  const int ST_i[4] = {0, 12288, 15360, 16128};
  const float Wf  = (float)W_i[l];
  const float THf = (float)TH_i[l];

  bfraw* prow = proj + (size_t)qg * 768;

  // ---- joint softmax over 32 logits of (qg, h) — shfl in 32-lane group ----
  const float logit = (p < 4) ? bf2f(prow[512 + h * 16 + l * 4 + p])
                              : bf2f(prow[640 + h * 16 + l * 4 + (p - 4)]);
  float mx = logit;
#pragma unroll
  for (int m = 16; m >= 1; m >>= 1) mx = fmaxf(mx, __shfl_xor(mx, m));
  const float e = __expf(logit - mx);
  float ssum = e;
#pragma unroll
  for (int m = 16; m >= 1; m >>= 1) ssum += __shfl_xor(ssum, m);
  const float attn = e / ssum;

  // ---- sampling location + bilinear corner descriptors ----
  float rx, ry;
  if constexpr (VF32) {
    rx = ((const float*)refp)[(size_t)(qg * 4 + l) * 2 + 0];
    ry = ((const float*)refp)[(size_t)(qg * 4 + l) * 2 + 1];
  } else {
    rx = loadx(refp, (size_t)(qg * 4 + l) * 2 + 0, f32m);
    ry = loadx(refp, (size_t)(qg * 4 + l) * 2 + 1, f32m);
  }
  float ox, oy;
  if (p < 4) {
    ox = bf2f(prow[h * 32 + l * 8 + p * 2 + 0]) / Wf;
    oy = bf2f(prow[h * 32 + l * 8 + p * 2 + 1]) / THf;
  } else {
    const int pj = p - 4, tw = pj >> 1, j = pj & 1;
    float tx, ty;
    if constexpr (VF32) {
      tx = ((const float*)toff)[(size_t)(qg * 4 + l) * 4 + tw * 2 + 0];
      ty = ((const float*)toff)[(size_t)(qg * 4 + l) * 4 + tw * 2 + 1];
    } else {
      tx = loadx(toff, (size_t)(qg * 4 + l) * 4 + tw * 2 + 0, f32m);
      ty = loadx(toff, (size_t)(qg * 4 + l) * 4 + tw * 2 + 1, f32m);
    }
    ox = tx + bf2f(prow[256 + h * 32 + l * 8 + tw * 4 + j * 2 + 0]) / Wf;
    oy = ty + bf2f(prow[256 + h * 32 + l * 8 + tw * 4 + j * 2 + 1]) / THf;
  }
  const float x = (rx + ox) * Wf - 0.5f;   // grid_sample align_corners=False
  const float y = (ry + oy) * THf - 0.5f;
  const float x0f = floorf(x), y0f = floorf(y);
  const float lx = x - x0f, ly = y - y0f;
  const int x0 = (int)x0f, y0 = (int)y0f;
  const int Wg = W_i[l], THg = TH_i[l], ST = ST_i[l];
  const float cwx[2] = {1.f - lx, lx};
  const float cwy[2] = {1.f - ly, ly};
#pragma unroll
  for (int c = 0; c < 4; ++c) {
    const int xi = x0 + (c & 1), yi = y0 + (c >> 1);
    const bool inb = (xi >= 0) & (xi < Wg) & (yi >= 0) & (yi < THg);
    const int xc = min(max(xi, 0), Wg - 1);
    const int yc = min(max(yi, 0), THg - 1);
    s_idx[tid][c] = ST + yc * Wg + xc;
    s_w[tid][c] = inb ? (attn * cwx[c & 1] * cwy[c >> 1]) : 0.f;
  }
  __syncthreads();

  // ---- gather: thread = (qi, pt-group pg 0..7, ch-quad chq 0..3) ----
  {
    const int pg = sp >> 2;
    const int chq = sp & 3;
    int   idx[16];
    float ww[16];
#pragma unroll
    for (int pt = 0; pt < 4; ++pt) {
      const int ds = qi * 32 + pg * 4 + pt;
#pragma unroll
      for (int c = 0; c < 4; ++c) { idx[pt * 4 + c] = s_idx[ds][c]; ww[pt * 4 + c] = s_w[ds][c]; }
    }
    float acc[8] = {};
    if constexpr (VF32) {
      // f32 head-major value: slice base uniform (SGPR), 32-bit voffset.
      const char* vbase = (const char*)value + (size_t)h * 16320 * 128;
      const unsigned cb = (unsigned)(chq << 5);
#pragma unroll
      for (int i = 0; i < 16; ++i) {
        const unsigned off = (((unsigned)idx[i]) << 7) | cb;
        const float4 a4 = *(const float4*)(vbase + off);
        const float4 b4 = *(const float4*)(vbase + off + 16);
        const float w = ww[i];
        acc[0] += w * a4.x; acc[1] += w * a4.y;
        acc[2] += w * a4.z; acc[3] += w * a4.w;
        acc[4] += w * b4.x; acc[5] += w * b4.y;
        acc[6] += w * b4.z; acc[7] += w * b4.w;
      }
    } else {
      const bfraw* vb = (const bfraw*)value + h * 32 + chq * 8;
      uint4 vv[16];
#pragma unroll
      for (int i = 0; i < 16; ++i) vv[i] = *(const uint4*)(vb + (size_t)idx[i] * 256);
#pragma unroll
      for (int i = 0; i < 16; ++i) {
        const float w = ww[i]; const uint4 v = vv[i];
        acc[0] += w * lo16f(v.x); acc[1] += w * hi16f(v.x);
        acc[2] += w * lo16f(v.y); acc[3] += w * hi16f(v.y);
        acc[4] += w * lo16f(v.z); acc[5] += w * hi16f(v.z);
        acc[6] += w * lo16f(v.w); acc[7] += w * hi16f(v.w);
      }
    }
    // reduce over pg (lane bits 2..4 — stays within the 32-lane group)
#pragma unroll
    for (int m = 4; m <= 16; m <<= 1)
#pragma unroll
      for (int r = 0; r < 8; ++r)
        acc[r] += __shfl_xor(acc[r], m);
    if (pg == 0) {   // core overlay: prow[h*32 + chq*8 .. +8) := slice (bf16)
      uint4 pk;
      pk.x = pk2(acc[0], acc[1]);
      pk.y = pk2(acc[2], acc[3]);
      pk.z = pk2(acc[4], acc[5]);
      pk.w = pk2(acc[6], acc[7]);
      *(uint4*)(prow + h * 32 + chq * 8) = pk;
    }
  }
}

extern "C" void kernel_launch(void* const* d_in, const int* in_sizes, int n_in,
                              void* d_out, int out_size, void* d_ws, size_t ws_size,
                              hipStream_t stream)
{
  const void* query  = d_in[0];
  const void* refp   = d_in[1];
  const void* toff   = d_in[2];
  const void* inflat = d_in[3];
  const void* W_so  = d_in[6];
  const void* b_so  = d_in[7];
  const void* W_tso = d_in[8];
  const void* b_tso = d_in[9];
  const void* W_aw  = d_in[10];
  const void* b_aw  = d_in[11];
  const void* W_taw = d_in[12];
  const void* b_taw = d_in[13];
  const void* W_v   = d_in[14];
  const void* b_v   = d_in[15];
  const void* W_o   = d_in[16];
  const void* b_o   = d_in[17];

  const int Lq = 16320;
  const size_t WT_B   = (size_t)1280 * 256 * 2;     //   655,360
  const size_t BCAT_B = 768 * 4;                    //     3,072
  const size_t REFP_B = (size_t)Lq * 8 * 4;         //   522,240
  const size_t TOFF_B = (size_t)Lq * 16 * 4;        // 1,044,480
  const size_t VALF_B = (size_t)8 * Lq * 32 * 4;    // 16,711,680 (f32 head-major)
  const size_t VALB_B = (size_t)Lq * 256 * 2;       //  8,355,840 (bf16 fallback)
  const size_t PROJ_B = (size_t)Lq * 768 * 2;       // 25,067,520

  const size_t need_f32 = WT_B + BCAT_B + REFP_B + TOFF_B + VALF_B + PROJ_B; // ~44.0 MB
  const int vf32 = (ws_size >= need_f32) ? 1 : 0;

  char* wp = (char*)d_ws;
  bfraw* WT   = (bfraw*)wp; wp += WT_B;
  float* bcat = (float*)wp; wp += BCAT_B;

  const dim3 blk(256);
  if (vf32) {
    float* refpF = (float*)wp; wp += REFP_B;
    float* toffF = (float*)wp; wp += TOFF_B;
    void*  val   = (void*)wp;  wp += VALF_B;
    bfraw* proj  = (bfraw*)wp;

    prep_k<<<dim3(2813), blk, 0, stream>>>(W_v, W_so, W_tso, W_aw, W_taw, W_o,
                                           b_so, b_tso, b_aw, b_taw,
                                           refp, toff, WT, bcat, refpF, toffF, query);
    gemmVP_k<<<dim3(128, 8), blk, 0, stream>>>(inflat, query, WT, b_v, bcat, val, proj, Lq, 1);
    sampler_k<1><<<dim3(Lq / 8, 8), blk, 0, stream>>>(proj, val, refpF, toffF, query);
    gemmO_k<<<dim3(128, 2), blk, 0, stream>>>(proj, WT, b_o, d_out, query, Lq);
  } else {
    void*  val  = (void*)wp; wp += VALB_B;
    bfraw* proj = (bfraw*)wp;

    prep_k<<<dim3(1283), blk, 0, stream>>>(W_v, W_so, W_tso, W_aw, W_taw, W_o,
                                           b_so, b_tso, b_aw, b_taw,
                                           refp, toff, WT, bcat, (float*)val, (float*)val, query);
    gemmVP_k<<<dim3(128, 8), blk, 0, stream>>>(inflat, query, WT, b_v, bcat, val, proj, Lq, 0);
    sampler_k<0><<<dim3(Lq / 8, 8), blk, 0, stream>>>(proj, val, refp, toff, query);
    gemmO_k<<<dim3(128, 2), blk, 0, stream>>>(proj, WT, b_o, d_out, query, Lq);
  }
}

// Round 3
// 232.705 us; speedup vs baseline: 1.1814x; 1.1814x over previous
//
#include <hip/hip_runtime.h>

// ---------------------------------------------------------------------------
// TemporalDifferentModuleMSDeformAttnVIZ — MI355X (gfx950)
// Round 13: post-mortem of R12 (f32 value): VALUBusy 76->43% as predicted,
// but FETCH 54->94MB (f32 value doubled per-head live set 1.04->2.09MB and
// load count 16->32) -> gather went latency-bound, 89.5->115.5us. Revert to
// bf16 value (line-optimal: one 64B line per (pixel,head)), KEEP the cheap
// VALU cuts: (a) voteless sampler (refp/toff pre-converted f32 in prep),
// (b) head-major bf16 value [NH][16320][32] -> 32-bit gather addressing
// (1 shl vs 64-bit mad+carry per load), (c) explicit b128 LDS corner reads.
// Sampler numerics identical to R10 (bf16 value, f32 weights).
// Constants: D=256 NH=8 DH=32 L=4 NCP=4 TW=2 NTP=2 P=8
// Levels (T*H, W): TH={192,96,48,24} W={64,32,16,8} starts={0,12288,15360,16128}
// Lq=16320
// ---------------------------------------------------------------------------

typedef unsigned short bfraw;
typedef __attribute__((ext_vector_type(4))) float f32x4;
typedef __attribute__((ext_vector_type(8))) short bf16x8;

__device__ __forceinline__ float bf2f(bfraw u) {
  union { unsigned int i; float f; } v; v.i = ((unsigned int)u) << 16; return v.f;
}
__device__ __forceinline__ bfraw f2bf(float f) {
  union { float f; unsigned int i; } v; v.f = f;
  unsigned int x = v.i;
  return (bfraw)((x + 0x7FFFu + ((x >> 16) & 1u)) >> 16);  // RNE
}
__device__ __forceinline__ float lo16f(unsigned int w) {
  union { unsigned int i; float f; } v; v.i = w << 16; return v.f;
}
__device__ __forceinline__ float hi16f(unsigned int w) {
  union { unsigned int i; float f; } v; v.i = w & 0xFFFF0000u; return v.f;
}
__device__ __forceinline__ float loadx(const void* p, size_t i, int f32m) {
  if (f32m) return ((const float*)p)[i];
  else      return bf2f(((const bfraw*)p)[i]);
}
__device__ __forceinline__ unsigned pk2(float a, float b) {
  return (unsigned)f2bf(a) | ((unsigned)f2bf(b) << 16);
}

// Uniform dtype vote from the first 64 B of `query`. bf16 data: low half of
// each dword is ~N(0,1), |x| in [1e-3,16) w.p. ~0.9985 -> cnt~16. f32 data:
// low halves are mantissa bits -> ~5% in range -> cnt~1. Returns 1 = f32.
// Only kernels reading RAW inputs use this (prep/gemmVP/gemmO); sampler
// consumes pre-converted data and has no vote.
__device__ __forceinline__ int vote_f32(const void* q) {
  const unsigned* p = (const unsigned*)q;
  int cnt = 0;
#pragma unroll
  for (int i = 0; i < 16; ++i) {
    const float a = fabsf(lo16f(p[i]));
    cnt += (a > 0.0009765625f && a < 16.0f) ? 1 : 0;
  }
  return (cnt >= 8) ? 0 : 1;
}

// Prep: transposed bf16 weights + bias concat + refp/toff -> f32.
// WT rows 0..255 = W_v^T ; 256..1023 = Wproj^T (so|tso|aw|taw col order);
// 1024..1279 = W_o^T. Blocks 1280..1282: bcat[768] f32 = b_so|b_tso|b_aw|b_taw.
// Blocks 1283..1792: refpF (130560 f32). Blocks 1793..2812: toffF (261120 f32).
__global__ __launch_bounds__(256) void prep_k(
    const void* W_v, const void* W_so, const void* W_tso,
    const void* W_aw, const void* W_taw, const void* W_o,
    const void* b_so, const void* b_tso, const void* b_aw, const void* b_taw,
    const void* refp, const void* toff,
    bfraw* __restrict__ WT, float* __restrict__ bcat,
    float* __restrict__ refpF, float* __restrict__ toffF, const void* query)
{
  const int f32m = vote_f32(query);
  const int b = blockIdx.x, t = threadIdx.x;
  if (b < 1280) {
    float s;
    if (b < 256)       s = loadx(W_v, (size_t)t * 256 + b, f32m);
    else if (b < 1024) {
      const int rp = b - 256;
      if (rp < 256)      s = loadx(W_so,  (size_t)t * 256 + rp, f32m);
      else if (rp < 512) s = loadx(W_tso, (size_t)t * 256 + (rp - 256), f32m);
      else if (rp < 640) s = loadx(W_aw,  (size_t)t * 128 + (rp - 512), f32m);
      else               s = loadx(W_taw, (size_t)t * 128 + (rp - 640), f32m);
    } else               s = loadx(W_o,  (size_t)t * 256 + (b - 1024), f32m);
    WT[(size_t)b * 256 + t] = f2bf(s);
  } else if (b < 1283) {
    const int i = (b - 1280) * 256 + t;
    if (i < 768) {
      float s;
      if (i < 256)      s = loadx(b_so,  i, f32m);
      else if (i < 512) s = loadx(b_tso, i - 256, f32m);
      else if (i < 640) s = loadx(b_aw,  i - 512, f32m);
      else              s = loadx(b_taw, i - 640, f32m);
      bcat[i] = s;
    }
  } else if (b < 1793) {
    const int i = (b - 1283) * 256 + t;   // 510*256 == 130560 exactly
    refpF[i] = loadx(refp, i, f32m);
  } else {
    const int i = (b - 1793) * 256 + t;   // 1020*256 == 261120 exactly
    toffF[i] = loadx(toff, i, f32m);
  }
}

// Fused value + proj GEMM. 128x128 tiles, K=256, M=16320 (tail-guarded).
// blockIdx.y 0..1: value = inflat @ WvT^T + b_v -> bf16 HEAD-MAJOR
//   [NH][M][32]: elem ((col>>5)*M + row)*32 + (col&31)
// blockIdx.y 2..7: proj  = query @ WprojT^T + bcat -> bf16, ldc 768
__global__ __launch_bounds__(256) void gemmVP_k(
    const void* __restrict__ inflat, const void* __restrict__ query,
    const bfraw* __restrict__ WT, const void* __restrict__ b_v,
    const float* __restrict__ bcat,
    bfraw* __restrict__ valueOut, bfraw* __restrict__ proj, int M)
{
  __shared__ bfraw As[128][40];   // [m][k], +8 pad
  __shared__ bfraw Bs[128][40];   // [n][k]
  const int f32m = vote_f32(query);
  const int y = blockIdx.y;
  const void* A; int wtb, colb, bmode;
  if (y < 2) { A = inflat; wtb = y * 128;             colb = y * 128;       bmode = 1; }
  else       { A = query;  wtb = 256 + (y - 2) * 128; colb = (y - 2) * 128; bmode = 0; }

  const int bm = blockIdx.x * 128;
  const int tid = threadIdx.x;
  const int wave = tid >> 6, lane = tid & 63;
  const int quad = lane >> 4, l16 = lane & 15;
  const int mb = (wave >> 1) * 64, nb = (wave & 1) * 64;
  const int srow = tid >> 1;
  const int sk = (tid & 1) * 16;

  int lr = bm + srow; if (lr >= M) lr = M - 1;
  const size_t aoff = (size_t)lr * 256;

  f32x4 acc[4][4] = {{{0.f}}};

  for (int k0 = 0; k0 < 256; k0 += 32) {
    uint4 pa0, pa1;
    if (f32m) {
      const float* Af = (const float*)A + aoff + (k0 + sk);
      const float4 x0 = ((const float4*)Af)[0];
      const float4 x1 = ((const float4*)Af)[1];
      const float4 x2 = ((const float4*)Af)[2];
      const float4 x3 = ((const float4*)Af)[3];
      pa0.x = pk2(x0.x, x0.y); pa0.y = pk2(x0.z, x0.w);
      pa0.z = pk2(x1.x, x1.y); pa0.w = pk2(x1.z, x1.w);
      pa1.x = pk2(x2.x, x2.y); pa1.y = pk2(x2.z, x2.w);
      pa1.z = pk2(x3.x, x3.y); pa1.w = pk2(x3.z, x3.w);
    } else {
      const bfraw* Ab = (const bfraw*)A + aoff + (k0 + sk);
      pa0 = ((const uint4*)Ab)[0];
      pa1 = ((const uint4*)Ab)[1];
    }
    const bfraw* Bb = WT + (size_t)(wtb + srow) * 256 + (k0 + sk);
    const uint4 pb0 = ((const uint4*)Bb)[0];
    const uint4 pb1 = ((const uint4*)Bb)[1];
    *(uint4*)&As[srow][sk]     = pa0;
    *(uint4*)&As[srow][sk + 8] = pa1;
    *(uint4*)&Bs[srow][sk]     = pb0;
    *(uint4*)&Bs[srow][sk + 8] = pb1;
    __syncthreads();

    bf16x8 af[4], bf[4];
#pragma unroll
    for (int i = 0; i < 4; ++i)
      af[i] = *(const bf16x8*)&As[mb + i * 16 + l16][quad * 8];
#pragma unroll
    for (int j = 0; j < 4; ++j)
      bf[j] = *(const bf16x8*)&Bs[nb + j * 16 + l16][quad * 8];
#pragma unroll
    for (int i = 0; i < 4; ++i)
#pragma unroll
      for (int j = 0; j < 4; ++j)
        acc[i][j] = __builtin_amdgcn_mfma_f32_16x16x32_bf16(af[i], bf[j], acc[i][j], 0, 0, 0);
    __syncthreads();
  }

#pragma unroll
  for (int j = 0; j < 4; ++j) {
    const int col = colb + nb + j * 16 + l16;
    const float bb = bmode ? loadx(b_v, col, f32m) : bcat[col];
#pragma unroll
    for (int i = 0; i < 4; ++i) {
#pragma unroll
      for (int r = 0; r < 4; ++r) {
        const int lrow = bm + mb + i * 16 + quad * 4 + r;
        if (lrow < M) {
          const float vv = acc[i][j][r] + bb;
          if (!bmode)
            proj[(size_t)lrow * 768 + col] = f2bf(vv);
          else
            valueOut[((unsigned)(col >> 5) * (unsigned)M + (unsigned)lrow) * 32u
                     + (unsigned)(col & 31)] = f2bf(vv);
        }
      }
    }
  }
}

// O-projection GEMM: out[0..M) = core @ W_o + b_o; core = proj rows cols[0,256)
// (bf16, stride 768, written by sampler overlay). C dtype per vote.
__global__ __launch_bounds__(256) void gemmO_k(
    const bfraw* __restrict__ proj, const bfraw* __restrict__ WT,
    const void* __restrict__ b_o, void* __restrict__ Cout,
    const void* __restrict__ query, int M)
{
  __shared__ bfraw As[128][40];
  __shared__ bfraw Bs[128][40];
  const int f32m = vote_f32(query);
  const int bm = blockIdx.x * 128;
  const int bn = blockIdx.y * 128;
  const int tid = threadIdx.x;
  const int wave = tid >> 6, lane = tid & 63;
  const int quad = lane >> 4, l16 = lane & 15;
  const int mb = (wave >> 1) * 64, nb = (wave & 1) * 64;
  const int srow = tid >> 1;
  const int sk = (tid & 1) * 16;

  int lr = bm + srow; if (lr >= M) lr = M - 1;
  const size_t aoff = (size_t)lr * 768;

  f32x4 acc[4][4] = {{{0.f}}};

  for (int k0 = 0; k0 < 256; k0 += 32) {
    const bfraw* Ab = proj + aoff + (k0 + sk);
    const uint4 pa0 = ((const uint4*)Ab)[0];
    const uint4 pa1 = ((const uint4*)Ab)[1];
    const bfraw* Bb = WT + (size_t)(1024 + bn + srow) * 256 + (k0 + sk);
    const uint4 pb0 = ((const uint4*)Bb)[0];
    const uint4 pb1 = ((const uint4*)Bb)[1];
    *(uint4*)&As[srow][sk]     = pa0;
    *(uint4*)&As[srow][sk + 8] = pa1;
    *(uint4*)&Bs[srow][sk]     = pb0;
    *(uint4*)&Bs[srow][sk + 8] = pb1;
    __syncthreads();

    bf16x8 af[4], bf[4];
#pragma unroll
    for (int i = 0; i < 4; ++i)
      af[i] = *(const bf16x8*)&As[mb + i * 16 + l16][quad * 8];
#pragma unroll
    for (int j = 0; j < 4; ++j)
      bf[j] = *(const bf16x8*)&Bs[nb + j * 16 + l16][quad * 8];
#pragma unroll
    for (int i = 0; i < 4; ++i)
#pragma unroll
      for (int j = 0; j < 4; ++j)
        acc[i][j] = __builtin_amdgcn_mfma_f32_16x16x32_bf16(af[i], bf[j], acc[i][j], 0, 0, 0);
    __syncthreads();
  }

#pragma unroll
  for (int j = 0; j < 4; ++j) {
    const int col = bn + nb + j * 16 + l16;
    const float bb = loadx(b_o, col, f32m);
#pragma unroll
    for (int i = 0; i < 4; ++i) {
#pragma unroll
      for (int r = 0; r < 4; ++r) {
        const int lrow = bm + mb + i * 16 + quad * 4 + r;
        if (lrow < M) {
          const float v = acc[i][j][r] + bb;
          if (f32m) ((float*)Cout)[(size_t)lrow * 256 + col] = v;
          else      ((bfraw*)Cout)[(size_t)lrow * 256 + col] = f2bf(v);
        }
      }
    }
  }
}

// Sampler, head-major: grid (2040, 8); block = 8 queries x head blockIdx.y.
// x-major dispatch sweeps heads -> live value working set ~1.04MB/head
// (bf16 head-major [NH][16320][32], 64B per pixel = exactly one cache line).
// Voteless: refp/toff are pre-converted f32. Gather addressing is 32-bit:
// byte off = (idx<<6)|(chq<<4) against an SGPR head base.
// proj row (768 bf16): [0,256) cso | [256,512) tso | [512,640) caw |
// [640,768) taw. Writes core slice (bf16, 32ch) over prow[h*32 .. h*32+32).
__global__ __launch_bounds__(256, 4) void sampler_k(
    bfraw* __restrict__ proj, const bfraw* __restrict__ value,
    const float* __restrict__ refp, const float* __restrict__ toff)
{
  __shared__ __align__(16) int   s_idx[256][4];  // clamped pixel index
  __shared__ __align__(16) float s_w[256][4];    // attn*bilinear, 0 if OOB

  const int h = blockIdx.y;
  const int tid = threadIdx.x;
  const int qi = tid >> 5;         // query-in-block 0..7
  const int sp = tid & 31;         // point-in-head
  const int l = sp >> 3;           // level
  const int p = sp & 7;            // 0..3 current, 4..7 temporal
  const int qg = blockIdx.x * 8 + qi;

  const int W_i[4]  = {64, 32, 16, 8};
  const int TH_i[4] = {192, 96, 48, 24};
  const int ST_i[4] = {0, 12288, 15360, 16128};
  const float Wf  = (float)W_i[l];
  const float THf = (float)TH_i[l];

  bfraw* prow = proj + (size_t)qg * 768;

  // ---- joint softmax over 32 logits of (qg, h) — shfl in 32-lane group ----
  const float logit = (p < 4) ? bf2f(prow[512 + h * 16 + l * 4 + p])
                              : bf2f(prow[640 + h * 16 + l * 4 + (p - 4)]);
  float mx = logit;
#pragma unroll
  for (int m = 16; m >= 1; m >>= 1) mx = fmaxf(mx, __shfl_xor(mx, m));
  const float e = __expf(logit - mx);
  float ssum = e;
#pragma unroll
  for (int m = 16; m >= 1; m >>= 1) ssum += __shfl_xor(ssum, m);
  const float attn = e / ssum;

  // ---- sampling location + bilinear corner descriptors ----
  const float rx = refp[(unsigned)(qg * 4 + l) * 2 + 0];
  const float ry = refp[(unsigned)(qg * 4 + l) * 2 + 1];
  float ox, oy;
  if (p < 4) {
    ox = bf2f(prow[h * 32 + l * 8 + p * 2 + 0]) / Wf;
    oy = bf2f(prow[h * 32 + l * 8 + p * 2 + 1]) / THf;
  } else {
    const int pj = p - 4, tw = pj >> 1, j = pj & 1;
    ox = toff[(unsigned)(qg * 4 + l) * 4 + tw * 2 + 0] +
         bf2f(prow[256 + h * 32 + l * 8 + tw * 4 + j * 2 + 0]) / Wf;
    oy = toff[(unsigned)(qg * 4 + l) * 4 + tw * 2 + 1] +
         bf2f(prow[256 + h * 32 + l * 8 + tw * 4 + j * 2 + 1]) / THf;
  }
  const float x = (rx + ox) * Wf - 0.5f;   // grid_sample align_corners=False
  const float y = (ry + oy) * THf - 0.5f;
  const float x0f = floorf(x), y0f = floorf(y);
  const float lx = x - x0f, ly = y - y0f;
  const int x0 = (int)x0f, y0 = (int)y0f;
  const int Wg = W_i[l], THg = TH_i[l], ST = ST_i[l];
  const float cwx[2] = {1.f - lx, lx};
  const float cwy[2] = {1.f - ly, ly};
#pragma unroll
  for (int c = 0; c < 4; ++c) {
    const int xi = x0 + (c & 1), yi = y0 + (c >> 1);
    const bool inb = (xi >= 0) & (xi < Wg) & (yi >= 0) & (yi < THg);
    const int xc = min(max(xi, 0), Wg - 1);
    const int yc = min(max(yi, 0), THg - 1);
    s_idx[tid][c] = ST + yc * Wg + xc;
    s_w[tid][c] = inb ? (attn * cwx[c & 1] * cwy[c >> 1]) : 0.f;
  }
  __syncthreads();

  // ---- gather: thread = (qi, pt-group pg 0..7, ch-quad chq 0..3) ----
  {
    const int pg = sp >> 2;
    const int chq = sp & 3;
    // head base: 16320*32 bf16 elements per head (1,044,480 B) — SGPR base,
    // per-lane 32-bit byte offset (idx<<6)|(chq<<4).
    const char* vb = (const char*)(value + (unsigned)h * (16320u * 32u));
    const unsigned cb = (unsigned)(chq << 4);
    int   idx[16];
    float ww[16];
#pragma unroll
    for (int pt = 0; pt < 4; ++pt) {
      const int ds = qi * 32 + pg * 4 + pt;
      const int4   ia = *(const int4*)&s_idx[ds][0];    // ds_read_b128
      const float4 wa = *(const float4*)&s_w[ds][0];    // ds_read_b128
      idx[pt * 4 + 0] = ia.x; idx[pt * 4 + 1] = ia.y;
      idx[pt * 4 + 2] = ia.z; idx[pt * 4 + 3] = ia.w;
      ww[pt * 4 + 0] = wa.x; ww[pt * 4 + 1] = wa.y;
      ww[pt * 4 + 2] = wa.z; ww[pt * 4 + 3] = wa.w;
    }
    uint4 vv[16];
#pragma unroll
    for (int i = 0; i < 16; ++i)
      vv[i] = *(const uint4*)(vb + ((((unsigned)idx[i]) << 6) | cb));
    float acc[8] = {};
#pragma unroll
    for (int i = 0; i < 16; ++i) {
      const float w = ww[i]; const uint4 v = vv[i];
      acc[0] += w * lo16f(v.x); acc[1] += w * hi16f(v.x);
      acc[2] += w * lo16f(v.y); acc[3] += w * hi16f(v.y);
      acc[4] += w * lo16f(v.z); acc[5] += w * hi16f(v.z);
      acc[6] += w * lo16f(v.w); acc[7] += w * hi16f(v.w);
    }
    // reduce over pg (lane bits 2..4 — stays within the 32-lane group)
#pragma unroll
    for (int m = 4; m <= 16; m <<= 1)
#pragma unroll
      for (int r = 0; r < 8; ++r)
        acc[r] += __shfl_xor(acc[r], m);
    if (pg == 0) {   // core overlay: prow[h*32 + chq*8 .. +8) := slice (bf16)
      uint4 pk;
      pk.x = pk2(acc[0], acc[1]);
      pk.y = pk2(acc[2], acc[3]);
      pk.z = pk2(acc[4], acc[5]);
      pk.w = pk2(acc[6], acc[7]);
      *(uint4*)(prow + h * 32 + chq * 8) = pk;
    }
  }
}

extern "C" void kernel_launch(void* const* d_in, const int* in_sizes, int n_in,
                              void* d_out, int out_size, void* d_ws, size_t ws_size,
                              hipStream_t stream)
{
  const void* query  = d_in[0];
  const void* refp   = d_in[1];
  const void* toff   = d_in[2];
  const void* inflat = d_in[3];
  const void* W_so  = d_in[6];
  const void* b_so  = d_in[7];
  const void* W_tso = d_in[8];
  const void* b_tso = d_in[9];
  const void* W_aw  = d_in[10];
  const void* b_aw  = d_in[11];
  const void* W_taw = d_in[12];
  const void* b_taw = d_in[13];
  const void* W_v   = d_in[14];
  const void* b_v   = d_in[15];
  const void* W_o   = d_in[16];
  const void* b_o   = d_in[17];

  const int Lq = 16320;
  // ws layout: WT bf16[1280][256] | bcat f32[768] | refpF f32[130560] |
  //            toffF f32[261120] | value bf16 head-major [8][Lq][32] |
  //            proj bf16 [Lq][768]   — total ~35.7 MB (R12 proved ws>=44MB)
  const size_t WT_B   = (size_t)1280 * 256 * 2;     //   655,360
  const size_t BCAT_B = 768 * 4;                    //     3,072
  const size_t REFP_B = (size_t)Lq * 8 * 4;         //   522,240
  const size_t TOFF_B = (size_t)Lq * 16 * 4;        // 1,044,480
  const size_t VAL_B  = (size_t)8 * Lq * 32 * 2;    //  8,355,840
  (void)ws_size;

  char* wp = (char*)d_ws;
  bfraw* WT    = (bfraw*)wp; wp += WT_B;
  float* bcat  = (float*)wp; wp += BCAT_B;
  float* refpF = (float*)wp; wp += REFP_B;
  float* toffF = (float*)wp; wp += TOFF_B;
  bfraw* value = (bfraw*)wp; wp += VAL_B;
  bfraw* proj  = (bfraw*)wp;

  const dim3 blk(256);
  prep_k<<<dim3(2813), blk, 0, stream>>>(W_v, W_so, W_tso, W_aw, W_taw, W_o,
                                         b_so, b_tso, b_aw, b_taw,
                                         refp, toff, WT, bcat, refpF, toffF, query);
  gemmVP_k<<<dim3(128, 8), blk, 0, stream>>>(inflat, query, WT, b_v, bcat, value, proj, Lq);
  sampler_k<<<dim3(Lq / 8, 8), blk, 0, stream>>>(proj, value, refpF, toffF);
  gemmO_k<<<dim3(128, 2), blk, 0, stream>>>(proj, WT, b_o, d_out, query, Lq);
}

// Round 4
// 226.905 us; speedup vs baseline: 1.2116x; 1.0256x over previous
//
#include <hip/hip_runtime.h>

// ---------------------------------------------------------------------------
// TemporalDifferentModuleMSDeformAttnVIZ — MI355X (gfx950)
// Round 14: GEMM-side de-conversion. R13 landed sampler 89.5->70.9us (as
// predicted); top-5 now all-sampler => every other dispatch <70us. Theory:
// gemmVP is conversion-bound — f32 inputs force ~640 VALU ops/thread of
// f32->bf16 pk2 packing (~2x its MFMA issue time) + 2x A-read bytes.
// Fix: prep materializes queryB/inflatB (bf16) once (~50MB stream, +8us);
// gemmVP A-path becomes pure uint4 bf16 load (0 conv, 0 vote); b_v/b_o
// moved into bcat so gemmVP is voteless. Numerics bit-identical (same RNE).
// ws gates: base 35.65MB (R13 behavior) | +queryB 44.01MB (R12-proven) |
// +inflatB 52.36MB. Sampler unchanged from R13.
// Constants: D=256 NH=8 DH=32 L=4 NCP=4 TW=2 NTP=2 P=8
// Levels (T*H, W): TH={192,96,48,24} W={64,32,16,8} starts={0,12288,15360,16128}
// Lq=16320
// ---------------------------------------------------------------------------

typedef unsigned short bfraw;
typedef __attribute__((ext_vector_type(4))) float f32x4;
typedef __attribute__((ext_vector_type(8))) short bf16x8;

__device__ __forceinline__ float bf2f(bfraw u) {
  union { unsigned int i; float f; } v; v.i = ((unsigned int)u) << 16; return v.f;
}
__device__ __forceinline__ bfraw f2bf(float f) {
  union { float f; unsigned int i; } v; v.f = f;
  unsigned int x = v.i;
  return (bfraw)((x + 0x7FFFu + ((x >> 16) & 1u)) >> 16);  // RNE
}
__device__ __forceinline__ float lo16f(unsigned int w) {
  union { unsigned int i; float f; } v; v.i = w << 16; return v.f;
}
__device__ __forceinline__ float hi16f(unsigned int w) {
  union { unsigned int i; float f; } v; v.i = w & 0xFFFF0000u; return v.f;
}
__device__ __forceinline__ float loadx(const void* p, size_t i, int f32m) {
  if (f32m) return ((const float*)p)[i];
  else      return bf2f(((const bfraw*)p)[i]);
}
__device__ __forceinline__ unsigned pk2(float a, float b) {
  return (unsigned)f2bf(a) | ((unsigned)f2bf(b) << 16);
}

// Uniform dtype vote from the first 64 B of `query`. bf16 data: low half of
// each dword is ~N(0,1), |x| in [1e-3,16) w.p. ~0.9985 -> cnt~16. f32 data:
// low halves are mantissa bits -> ~5% in range -> cnt~1. Returns 1 = f32.
// Used by prep (input conversion), gemmO (output dtype), and gemmVP only on
// the no-workspace fallback path.
__device__ __forceinline__ int vote_f32(const void* q) {
  const unsigned* p = (const unsigned*)q;
  int cnt = 0;
#pragma unroll
  for (int i = 0; i < 16; ++i) {
    const float a = fabsf(lo16f(p[i]));
    cnt += (a > 0.0009765625f && a < 16.0f) ? 1 : 0;
  }
  return (cnt >= 8) ? 0 : 1;
}

// Convert 8 elements src[i0..i0+8) -> bf16 dst (copy if already bf16).
__device__ __forceinline__ void cvt8(const void* src, bfraw* dst, int i0, int f32m) {
  if (f32m) {
    const float4 a = ((const float4*)((const float*)src + i0))[0];
    const float4 b = ((const float4*)((const float*)src + i0))[1];
    uint4 o;
    o.x = pk2(a.x, a.y); o.y = pk2(a.z, a.w);
    o.z = pk2(b.x, b.y); o.w = pk2(b.z, b.w);
    *(uint4*)(dst + i0) = o;
  } else {
    *(uint4*)(dst + i0) = *(const uint4*)((const bfraw*)src + i0);
  }
}

// Prep. Block map:
//   [0,1280):    WT transpose (bf16). rows 0..255 W_v^T; 256..1023 Wproj^T
//                (so|tso|aw|taw); 1024..1279 W_o^T.
//   [1280,1285): bcat f32[1280] = b_so|b_tso|b_aw|b_taw | b_v | b_o
//   [1285,1795): refpF f32 (130560)
//   [1795,2815): toffF f32 (261120)
//   [2815,4855): queryB bf16 (4,177,920 elems; 2048/block)   [if qbf]
//   [4855,6895): inflatB bf16                                 [if ibf]
__global__ __launch_bounds__(256) void prep_k(
    const void* W_v, const void* W_so, const void* W_tso,
    const void* W_aw, const void* W_taw, const void* W_o,
    const void* b_so, const void* b_tso, const void* b_aw, const void* b_taw,
    const void* b_v, const void* b_o,
    const void* refp, const void* toff,
    const void* query, const void* inflat,
    bfraw* __restrict__ WT, float* __restrict__ bcat,
    float* __restrict__ refpF, float* __restrict__ toffF,
    bfraw* __restrict__ queryB, bfraw* __restrict__ inflatB,
    int qbf, int ibf)
{
  const int f32m = vote_f32(query);
  const int b = blockIdx.x, t = threadIdx.x;
  if (b < 1280) {
    float s;
    if (b < 256)       s = loadx(W_v, (size_t)t * 256 + b, f32m);
    else if (b < 1024) {
      const int rp = b - 256;
      if (rp < 256)      s = loadx(W_so,  (size_t)t * 256 + rp, f32m);
      else if (rp < 512) s = loadx(W_tso, (size_t)t * 256 + (rp - 256), f32m);
      else if (rp < 640) s = loadx(W_aw,  (size_t)t * 128 + (rp - 512), f32m);
      else               s = loadx(W_taw, (size_t)t * 128 + (rp - 640), f32m);
    } else               s = loadx(W_o,  (size_t)t * 256 + (b - 1024), f32m);
    WT[(size_t)b * 256 + t] = f2bf(s);
  } else if (b < 1285) {
    const int i = (b - 1280) * 256 + t;
    if (i < 1280) {
      float s;
      if (i < 256)       s = loadx(b_so,  i, f32m);
      else if (i < 512)  s = loadx(b_tso, i - 256, f32m);
      else if (i < 640)  s = loadx(b_aw,  i - 512, f32m);
      else if (i < 768)  s = loadx(b_taw, i - 640, f32m);
      else if (i < 1024) s = loadx(b_v,   i - 768, f32m);
      else               s = loadx(b_o,   i - 1024, f32m);
      bcat[i] = s;
    }
  } else if (b < 1795) {
    const int i = (b - 1285) * 256 + t;   // 510*256 == 130560 exactly
    refpF[i] = loadx(refp, i, f32m);
  } else if (b < 2815) {
    const int i = (b - 1795) * 256 + t;   // 1020*256 == 261120 exactly
    toffF[i] = loadx(toff, i, f32m);
  } else if (b < 4855) {
    if (!qbf) return;
    cvt8(query, queryB, (b - 2815) * 2048 + t * 8, f32m);
  } else {
    if (!ibf) return;
    cvt8(inflat, inflatB, (b - 4855) * 2048 + t * 8, f32m);
  }
}

// Fused value + proj GEMM. 128x128 tiles, K=256, M=16320 (tail-guarded).
// blockIdx.y 0..1: value = inflat @ WvT^T + b_v -> bf16 HEAD-MAJOR
//   [NH][M][32]: elem ((col>>5)*M + row)*32 + (col&31)
// blockIdx.y 2..7: proj  = query @ WprojT^T + bcat -> bf16, ldc 768
// A source: bf16 pre-converted (queryB/inflatB) when flag set, else raw
// (f32 pk2-pack or bf16 direct per vote) — R13 fallback.
__global__ __launch_bounds__(256) void gemmVP_k(
    const void* __restrict__ inflat, const void* __restrict__ query,
    const bfraw* __restrict__ inflatB, const bfraw* __restrict__ queryB,
    const bfraw* __restrict__ WT, const float* __restrict__ bcat,
    bfraw* __restrict__ valueOut, bfraw* __restrict__ proj, int M,
    int ibf, int qbf)
{
  __shared__ bfraw As[128][40];   // [m][k], +8 pad
  __shared__ bfraw Bs[128][40];   // [n][k]
  const int y = blockIdx.y;
  const void* Araw; const bfraw* Abf; int wtb, colb, bmode, abf;
  if (y < 2) { Araw = inflat; Abf = inflatB; abf = ibf;
               wtb = y * 128;             colb = y * 128;       bmode = 1; }
  else       { Araw = query;  Abf = queryB;  abf = qbf;
               wtb = 256 + (y - 2) * 128; colb = (y - 2) * 128; bmode = 0; }
  const int f32m = abf ? 0 : vote_f32(query);

  const int bm = blockIdx.x * 128;
  const int tid = threadIdx.x;
  const int wave = tid >> 6, lane = tid & 63;
  const int quad = lane >> 4, l16 = lane & 15;
  const int mb = (wave >> 1) * 64, nb = (wave & 1) * 64;
  const int srow = tid >> 1;
  const int sk = (tid & 1) * 16;

  int lr = bm + srow; if (lr >= M) lr = M - 1;
  const size_t aoff = (size_t)lr * 256;

  f32x4 acc[4][4] = {{{0.f}}};

  for (int k0 = 0; k0 < 256; k0 += 32) {
    uint4 pa0, pa1;
    if (abf) {
      const bfraw* Ab = Abf + aoff + (k0 + sk);
      pa0 = ((const uint4*)Ab)[0];
      pa1 = ((const uint4*)Ab)[1];
    } else if (f32m) {
      const float* Af = (const float*)Araw + aoff + (k0 + sk);
      const float4 x0 = ((const float4*)Af)[0];
      const float4 x1 = ((const float4*)Af)[1];
      const float4 x2 = ((const float4*)Af)[2];
      const float4 x3 = ((const float4*)Af)[3];
      pa0.x = pk2(x0.x, x0.y); pa0.y = pk2(x0.z, x0.w);
      pa0.z = pk2(x1.x, x1.y); pa0.w = pk2(x1.z, x1.w);
      pa1.x = pk2(x2.x, x2.y); pa1.y = pk2(x2.z, x2.w);
      pa1.z = pk2(x3.x, x3.y); pa1.w = pk2(x3.z, x3.w);
    } else {
      const bfraw* Ab = (const bfraw*)Araw + aoff + (k0 + sk);
      pa0 = ((const uint4*)Ab)[0];
      pa1 = ((const uint4*)Ab)[1];
    }
    const bfraw* Bb = WT + (size_t)(wtb + srow) * 256 + (k0 + sk);
    const uint4 pb0 = ((const uint4*)Bb)[0];
    const uint4 pb1 = ((const uint4*)Bb)[1];
    *(uint4*)&As[srow][sk]     = pa0;
    *(uint4*)&As[srow][sk + 8] = pa1;
    *(uint4*)&Bs[srow][sk]     = pb0;
    *(uint4*)&Bs[srow][sk + 8] = pb1;
    __syncthreads();

    bf16x8 af[4], bf[4];
#pragma unroll
    for (int i = 0; i < 4; ++i)
      af[i] = *(const bf16x8*)&As[mb + i * 16 + l16][quad * 8];
#pragma unroll
    for (int j = 0; j < 4; ++j)
      bf[j] = *(const bf16x8*)&Bs[nb + j * 16 + l16][quad * 8];
#pragma unroll
    for (int i = 0; i < 4; ++i)
#pragma unroll
      for (int j = 0; j < 4; ++j)
        acc[i][j] = __builtin_amdgcn_mfma_f32_16x16x32_bf16(af[i], bf[j], acc[i][j], 0, 0, 0);
    __syncthreads();
  }

#pragma unroll
  for (int j = 0; j < 4; ++j) {
    const int col = colb + nb + j * 16 + l16;
    const float bb = bmode ? bcat[768 + col] : bcat[col];
#pragma unroll
    for (int i = 0; i < 4; ++i) {
#pragma unroll
      for (int r = 0; r < 4; ++r) {
        const int lrow = bm + mb + i * 16 + quad * 4 + r;
        if (lrow < M) {
          const float vv = acc[i][j][r] + bb;
          if (!bmode)
            proj[(size_t)lrow * 768 + col] = f2bf(vv);
          else
            valueOut[((unsigned)(col >> 5) * (unsigned)M + (unsigned)lrow) * 32u
                     + (unsigned)(col & 31)] = f2bf(vv);
        }
      }
    }
  }
}

// O-projection GEMM: out[0..M) = core @ W_o + b_o; core = proj rows cols[0,256)
// (bf16, stride 768, written by sampler overlay). C dtype per vote; b_o from
// bcat[1024..1280).
__global__ __launch_bounds__(256) void gemmO_k(
    const bfraw* __restrict__ proj, const bfraw* __restrict__ WT,
    const float* __restrict__ bcat, void* __restrict__ Cout,
    const void* __restrict__ query, int M)
{
  __shared__ bfraw As[128][40];
  __shared__ bfraw Bs[128][40];
  const int f32m = vote_f32(query);
  const int bm = blockIdx.x * 128;
  const int bn = blockIdx.y * 128;
  const int tid = threadIdx.x;
  const int wave = tid >> 6, lane = tid & 63;
  const int quad = lane >> 4, l16 = lane & 15;
  const int mb = (wave >> 1) * 64, nb = (wave & 1) * 64;
  const int srow = tid >> 1;
  const int sk = (tid & 1) * 16;

  int lr = bm + srow; if (lr >= M) lr = M - 1;
  const size_t aoff = (size_t)lr * 768;

  f32x4 acc[4][4] = {{{0.f}}};

  for (int k0 = 0; k0 < 256; k0 += 32) {
    const bfraw* Ab = proj + aoff + (k0 + sk);
    const uint4 pa0 = ((const uint4*)Ab)[0];
    const uint4 pa1 = ((const uint4*)Ab)[1];
    const bfraw* Bb = WT + (size_t)(1024 + bn + srow) * 256 + (k0 + sk);
    const uint4 pb0 = ((const uint4*)Bb)[0];
    const uint4 pb1 = ((const uint4*)Bb)[1];
    *(uint4*)&As[srow][sk]     = pa0;
    *(uint4*)&As[srow][sk + 8] = pa1;
    *(uint4*)&Bs[srow][sk]     = pb0;
    *(uint4*)&Bs[srow][sk + 8] = pb1;
    __syncthreads();

    bf16x8 af[4], bf[4];
#pragma unroll
    for (int i = 0; i < 4; ++i)
      af[i] = *(const bf16x8*)&As[mb + i * 16 + l16][quad * 8];
#pragma unroll
    for (int j = 0; j < 4; ++j)
      bf[j] = *(const bf16x8*)&Bs[nb + j * 16 + l16][quad * 8];
#pragma unroll
    for (int i = 0; i < 4; ++i)
#pragma unroll
      for (int j = 0; j < 4; ++j)
        acc[i][j] = __builtin_amdgcn_mfma_f32_16x16x32_bf16(af[i], bf[j], acc[i][j], 0, 0, 0);
    __syncthreads();
  }

#pragma unroll
  for (int j = 0; j < 4; ++j) {
    const int col = bn + nb + j * 16 + l16;
    const float bb = bcat[1024 + col];
#pragma unroll
    for (int i = 0; i < 4; ++i) {
#pragma unroll
      for (int r = 0; r < 4; ++r) {
        const int lrow = bm + mb + i * 16 + quad * 4 + r;
        if (lrow < M) {
          const float v = acc[i][j][r] + bb;
          if (f32m) ((float*)Cout)[(size_t)lrow * 256 + col] = v;
          else      ((bfraw*)Cout)[(size_t)lrow * 256 + col] = f2bf(v);
        }
      }
    }
  }
}

// Sampler, head-major (unchanged from R13): grid (2040, 8); block = 8 q x 1 h.
// bf16 head-major value [NH][16320][32] (1.04MB/head live set, 64B/pixel =
// one line). Voteless; refp/toff pre-converted f32. 32-bit gather addressing.
__global__ __launch_bounds__(256, 4) void sampler_k(
    bfraw* __restrict__ proj, const bfraw* __restrict__ value,
    const float* __restrict__ refp, const float* __restrict__ toff)
{
  __shared__ __align__(16) int   s_idx[256][4];  // clamped pixel index
  __shared__ __align__(16) float s_w[256][4];    // attn*bilinear, 0 if OOB

  const int h = blockIdx.y;
  const int tid = threadIdx.x;
  const int qi = tid >> 5;         // query-in-block 0..7
  const int sp = tid & 31;         // point-in-head
  const int l = sp >> 3;           // level
  const int p = sp & 7;            // 0..3 current, 4..7 temporal
  const int qg = blockIdx.x * 8 + qi;

  const int W_i[4]  = {64, 32, 16, 8};
  const int TH_i[4] = {192, 96, 48, 24};
  const int ST_i[4] = {0, 12288, 15360, 16128};
  const float Wf  = (float)W_i[l];
  const float THf = (float)TH_i[l];

  bfraw* prow = proj + (size_t)qg * 768;

  // ---- joint softmax over 32 logits of (qg, h) — shfl in 32-lane group ----
  const float logit = (p < 4) ? bf2f(prow[512 + h * 16 + l * 4 + p])
                              : bf2f(prow[640 + h * 16 + l * 4 + (p - 4)]);
  float mx = logit;
#pragma unroll
  for (int m = 16; m >= 1; m >>= 1) mx = fmaxf(mx, __shfl_xor(mx, m));
  const float e = __expf(logit - mx);
  float ssum = e;
#pragma unroll
  for (int m = 16; m >= 1; m >>= 1) ssum += __shfl_xor(ssum, m);
  const float attn = e / ssum;

  // ---- sampling location + bilinear corner descriptors ----
  const float rx = refp[(unsigned)(qg * 4 + l) * 2 + 0];
  const float ry = refp[(unsigned)(qg * 4 + l) * 2 + 1];
  float ox, oy;
  if (p < 4) {
    ox = bf2f(prow[h * 32 + l * 8 + p * 2 + 0]) / Wf;
    oy = bf2f(prow[h * 32 + l * 8 + p * 2 + 1]) / THf;
  } else {
    const int pj = p - 4, tw = pj >> 1, j = pj & 1;
    ox = toff[(unsigned)(qg * 4 + l) * 4 + tw * 2 + 0] +
         bf2f(prow[256 + h * 32 + l * 8 + tw * 4 + j * 2 + 0]) / Wf;
    oy = toff[(unsigned)(qg * 4 + l) * 4 + tw * 2 + 1] +
         bf2f(prow[256 + h * 32 + l * 8 + tw * 4 + j * 2 + 1]) / THf;
  }
  const float x = (rx + ox) * Wf - 0.5f;   // grid_sample align_corners=False
  const float y = (ry + oy) * THf - 0.5f;
  const float x0f = floorf(x), y0f = floorf(y);
  const float lx = x - x0f, ly = y - y0f;
  const int x0 = (int)x0f, y0 = (int)y0f;
  const int Wg = W_i[l], THg = TH_i[l], ST = ST_i[l];
  const float cwx[2] = {1.f - lx, lx};
  const float cwy[2] = {1.f - ly, ly};
#pragma unroll
  for (int c = 0; c < 4; ++c) {
    const int xi = x0 + (c & 1), yi = y0 + (c >> 1);
    const bool inb = (xi >= 0) & (xi < Wg) & (yi >= 0) & (yi < THg);
    const int xc = min(max(xi, 0), Wg - 1);
    const int yc = min(max(yi, 0), THg - 1);
    s_idx[tid][c] = ST + yc * Wg + xc;
    s_w[tid][c] = inb ? (attn * cwx[c & 1] * cwy[c >> 1]) : 0.f;
  }
  __syncthreads();

  // ---- gather: thread = (qi, pt-group pg 0..7, ch-quad chq 0..3) ----
  {
    const int pg = sp >> 2;
    const int chq = sp & 3;
    const char* vb = (const char*)(value + (unsigned)h * (16320u * 32u));
    const unsigned cb = (unsigned)(chq << 4);
    int   idx[16];
    float ww[16];
#pragma unroll
    for (int pt = 0; pt < 4; ++pt) {
      const int ds = qi * 32 + pg * 4 + pt;
      const int4   ia = *(const int4*)&s_idx[ds][0];    // ds_read_b128
      const float4 wa = *(const float4*)&s_w[ds][0];    // ds_read_b128
      idx[pt * 4 + 0] = ia.x; idx[pt * 4 + 1] = ia.y;
      idx[pt * 4 + 2] = ia.z; idx[pt * 4 + 3] = ia.w;
      ww[pt * 4 + 0] = wa.x; ww[pt * 4 + 1] = wa.y;
      ww[pt * 4 + 2] = wa.z; ww[pt * 4 + 3] = wa.w;
    }
    uint4 vv[16];
#pragma unroll
    for (int i = 0; i < 16; ++i)
      vv[i] = *(const uint4*)(vb + ((((unsigned)idx[i]) << 6) | cb));
    float acc[8] = {};
#pragma unroll
    for (int i = 0; i < 16; ++i) {
      const float w = ww[i]; const uint4 v = vv[i];
      acc[0] += w * lo16f(v.x); acc[1] += w * hi16f(v.x);
      acc[2] += w * lo16f(v.y); acc[3] += w * hi16f(v.y);
      acc[4] += w * lo16f(v.z); acc[5] += w * hi16f(v.z);
      acc[6] += w * lo16f(v.w); acc[7] += w * hi16f(v.w);
    }
    // reduce over pg (lane bits 2..4 — stays within the 32-lane group)
#pragma unroll
    for (int m = 4; m <= 16; m <<= 1)
#pragma unroll
      for (int r = 0; r < 8; ++r)
        acc[r] += __shfl_xor(acc[r], m);
    if (pg == 0) {   // core overlay: prow[h*32 + chq*8 .. +8) := slice (bf16)
      uint4 pk;
      pk.x = pk2(acc[0], acc[1]);
      pk.y = pk2(acc[2], acc[3]);
      pk.z = pk2(acc[4], acc[5]);
      pk.w = pk2(acc[6], acc[7]);
      *(uint4*)(prow + h * 32 + chq * 8) = pk;
    }
  }
}

extern "C" void kernel_launch(void* const* d_in, const int* in_sizes, int n_in,
                              void* d_out, int out_size, void* d_ws, size_t ws_size,
                              hipStream_t stream)
{
  const void* query  = d_in[0];
  const void* refp   = d_in[1];
  const void* toff   = d_in[2];
  const void* inflat = d_in[3];
  const void* W_so  = d_in[6];
  const void* b_so  = d_in[7];
  const void* W_tso = d_in[8];
  const void* b_tso = d_in[9];
  const void* W_aw  = d_in[10];
  const void* b_aw  = d_in[11];
  const void* W_taw = d_in[12];
  const void* b_taw = d_in[13];
  const void* W_v   = d_in[14];
  const void* b_v   = d_in[15];
  const void* W_o   = d_in[16];
  const void* b_o   = d_in[17];

  const int Lq = 16320;
  // ws layout: WT bf16[1280][256] | bcat f32[1280] | refpF f32[130560] |
  //   toffF f32[261120] | value bf16 [8][Lq][32] | proj bf16 [Lq][768] |
  //   queryB bf16 [Lq][256] | inflatB bf16 [Lq][256]
  const size_t WT_B   = (size_t)1280 * 256 * 2;     //    655,360
  const size_t BCAT_B = 1280 * 4;                   //      5,120
  const size_t REFP_B = (size_t)Lq * 8 * 4;         //    522,240
  const size_t TOFF_B = (size_t)Lq * 16 * 4;        //  1,044,480
  const size_t VAL_B  = (size_t)8 * Lq * 32 * 2;    //  8,355,840
  const size_t PROJ_B = (size_t)Lq * 768 * 2;       // 25,067,520
  const size_t QB_B   = (size_t)Lq * 256 * 2;       //  8,355,840
  const size_t base   = WT_B + BCAT_B + REFP_B + TOFF_B + VAL_B + PROJ_B; // 35,650,560

  const int qbf = (ws_size >= base + QB_B)     ? 1 : 0;  // 44,006,400 (R12-proven tier)
  const int ibf = (ws_size >= base + 2 * QB_B) ? 1 : 0;  // 52,362,240

  char* wp = (char*)d_ws;
  bfraw* WT     = (bfraw*)wp; wp += WT_B;
  float* bcat   = (float*)wp; wp += BCAT_B;
  float* refpF  = (float*)wp; wp += REFP_B;
  float* toffF  = (float*)wp; wp += TOFF_B;
  bfraw* value  = (bfraw*)wp; wp += VAL_B;
  bfraw* proj   = (bfraw*)wp; wp += PROJ_B;
  bfraw* queryB = (bfraw*)wp; wp += QB_B;   // valid only if qbf
  bfraw* inflatB= (bfraw*)wp;               // valid only if ibf

  const dim3 blk(256);
  const int prep_blocks = ibf ? 6895 : (qbf ? 4855 : 2815);
  prep_k<<<dim3(prep_blocks), blk, 0, stream>>>(
      W_v, W_so, W_tso, W_aw, W_taw, W_o,
      b_so, b_tso, b_aw, b_taw, b_v, b_o,
      refp, toff, query, inflat,
      WT, bcat, refpF, toffF, queryB, inflatB, qbf, ibf);
  gemmVP_k<<<dim3(128, 8), blk, 0, stream>>>(inflat, query, inflatB, queryB,
                                             WT, bcat, value, proj, Lq, ibf, qbf);
  sampler_k<<<dim3(Lq / 8, 8), blk, 0, stream>>>(proj, value, refpF, toffF);
  gemmO_k<<<dim3(128, 2), blk, 0, stream>>>(proj, WT, bcat, d_out, query, Lq);
}

// Round 5
// 221.575 us; speedup vs baseline: 1.2407x; 1.0241x over previous
//
#include <hip/hip_runtime.h>

// ---------------------------------------------------------------------------
// TemporalDifferentModuleMSDeformAttnVIZ — MI355X (gfx950)
// Round 15: sampler gather de-serialization. R14 evidence: VGPR_Count=36 —
// far below the ~100 needed to hold 16 gathered uint4 in flight -> compiler
// rolled the gather into ~2-outstanding-load batches = ~16 exposed L2 round
// trips/thread. Fix: (1) drop the (256,4) min-occupancy clamp (was capping
// VGPR<=128), (2) issue all 16 gathers as NAMED registers (two 8-load
// batches) before any consumption, (3) float2-packed consume to allow
// v_pk_fma_f32 formation. Numerics bit-identical. prep/gemmVP/gemmO
// unchanged from R14.
// Constants: D=256 NH=8 DH=32 L=4 NCP=4 TW=2 NTP=2 P=8
// Levels (T*H, W): TH={192,96,48,24} W={64,32,16,8} starts={0,12288,15360,16128}
// Lq=16320
// ---------------------------------------------------------------------------

typedef unsigned short bfraw;
typedef __attribute__((ext_vector_type(2))) float f32x2;
typedef __attribute__((ext_vector_type(4))) float f32x4;
typedef __attribute__((ext_vector_type(8))) short bf16x8;

__device__ __forceinline__ float bf2f(bfraw u) {
  union { unsigned int i; float f; } v; v.i = ((unsigned int)u) << 16; return v.f;
}
__device__ __forceinline__ bfraw f2bf(float f) {
  union { float f; unsigned int i; } v; v.f = f;
  unsigned int x = v.i;
  return (bfraw)((x + 0x7FFFu + ((x >> 16) & 1u)) >> 16);  // RNE
}
__device__ __forceinline__ float lo16f(unsigned int w) {
  union { unsigned int i; float f; } v; v.i = w << 16; return v.f;
}
__device__ __forceinline__ float hi16f(unsigned int w) {
  union { unsigned int i; float f; } v; v.i = w & 0xFFFF0000u; return v.f;
}
__device__ __forceinline__ float loadx(const void* p, size_t i, int f32m) {
  if (f32m) return ((const float*)p)[i];
  else      return bf2f(((const bfraw*)p)[i]);
}
__device__ __forceinline__ unsigned pk2(float a, float b) {
  return (unsigned)f2bf(a) | ((unsigned)f2bf(b) << 16);
}

// Uniform dtype vote from the first 64 B of `query`. bf16 data: low half of
// each dword is ~N(0,1), |x| in [1e-3,16) w.p. ~0.9985 -> cnt~16. f32 data:
// low halves are mantissa bits -> ~5% in range -> cnt~1. Returns 1 = f32.
__device__ __forceinline__ int vote_f32(const void* q) {
  const unsigned* p = (const unsigned*)q;
  int cnt = 0;
#pragma unroll
  for (int i = 0; i < 16; ++i) {
    const float a = fabsf(lo16f(p[i]));
    cnt += (a > 0.0009765625f && a < 16.0f) ? 1 : 0;
  }
  return (cnt >= 8) ? 0 : 1;
}

// Convert 8 elements src[i0..i0+8) -> bf16 dst (copy if already bf16).
__device__ __forceinline__ void cvt8(const void* src, bfraw* dst, int i0, int f32m) {
  if (f32m) {
    const float4 a = ((const float4*)((const float*)src + i0))[0];
    const float4 b = ((const float4*)((const float*)src + i0))[1];
    uint4 o;
    o.x = pk2(a.x, a.y); o.y = pk2(a.z, a.w);
    o.z = pk2(b.x, b.y); o.w = pk2(b.z, b.w);
    *(uint4*)(dst + i0) = o;
  } else {
    *(uint4*)(dst + i0) = *(const uint4*)((const bfraw*)src + i0);
  }
}

// Prep. Block map:
//   [0,1280):    WT transpose (bf16). rows 0..255 W_v^T; 256..1023 Wproj^T
//                (so|tso|aw|taw); 1024..1279 W_o^T.
//   [1280,1285): bcat f32[1280] = b_so|b_tso|b_aw|b_taw | b_v | b_o
//   [1285,1795): refpF f32 (130560)
//   [1795,2815): toffF f32 (261120)
//   [2815,4855): queryB bf16 (4,177,920 elems; 2048/block)   [if qbf]
//   [4855,6895): inflatB bf16                                 [if ibf]
__global__ __launch_bounds__(256) void prep_k(
    const void* W_v, const void* W_so, const void* W_tso,
    const void* W_aw, const void* W_taw, const void* W_o,
    const void* b_so, const void* b_tso, const void* b_aw, const void* b_taw,
    const void* b_v, const void* b_o,
    const void* refp, const void* toff,
    const void* query, const void* inflat,
    bfraw* __restrict__ WT, float* __restrict__ bcat,
    float* __restrict__ refpF, float* __restrict__ toffF,
    bfraw* __restrict__ queryB, bfraw* __restrict__ inflatB,
    int qbf, int ibf)
{
  const int f32m = vote_f32(query);
  const int b = blockIdx.x, t = threadIdx.x;
  if (b < 1280) {
    float s;
    if (b < 256)       s = loadx(W_v, (size_t)t * 256 + b, f32m);
    else if (b < 1024) {
      const int rp = b - 256;
      if (rp < 256)      s = loadx(W_so,  (size_t)t * 256 + rp, f32m);
      else if (rp < 512) s = loadx(W_tso, (size_t)t * 256 + (rp - 256), f32m);
      else if (rp < 640) s = loadx(W_aw,  (size_t)t * 128 + (rp - 512), f32m);
      else               s = loadx(W_taw, (size_t)t * 128 + (rp - 640), f32m);
    } else               s = loadx(W_o,  (size_t)t * 256 + (b - 1024), f32m);
    WT[(size_t)b * 256 + t] = f2bf(s);
  } else if (b < 1285) {
    const int i = (b - 1280) * 256 + t;
    if (i < 1280) {
      float s;
      if (i < 256)       s = loadx(b_so,  i, f32m);
      else if (i < 512)  s = loadx(b_tso, i - 256, f32m);
      else if (i < 640)  s = loadx(b_aw,  i - 512, f32m);
      else if (i < 768)  s = loadx(b_taw, i - 640, f32m);
      else if (i < 1024) s = loadx(b_v,   i - 768, f32m);
      else               s = loadx(b_o,   i - 1024, f32m);
      bcat[i] = s;
    }
  } else if (b < 1795) {
    const int i = (b - 1285) * 256 + t;   // 510*256 == 130560 exactly
    refpF[i] = loadx(refp, i, f32m);
  } else if (b < 2815) {
    const int i = (b - 1795) * 256 + t;   // 1020*256 == 261120 exactly
    toffF[i] = loadx(toff, i, f32m);
  } else if (b < 4855) {
    if (!qbf) return;
    cvt8(query, queryB, (b - 2815) * 2048 + t * 8, f32m);
  } else {
    if (!ibf) return;
    cvt8(inflat, inflatB, (b - 4855) * 2048 + t * 8, f32m);
  }
}

// Fused value + proj GEMM. 128x128 tiles, K=256, M=16320 (tail-guarded).
// blockIdx.y 0..1: value = inflat @ WvT^T + b_v -> bf16 HEAD-MAJOR
//   [NH][M][32]: elem ((col>>5)*M + row)*32 + (col&31)
// blockIdx.y 2..7: proj  = query @ WprojT^T + bcat -> bf16, ldc 768
__global__ __launch_bounds__(256) void gemmVP_k(
    const void* __restrict__ inflat, const void* __restrict__ query,
    const bfraw* __restrict__ inflatB, const bfraw* __restrict__ queryB,
    const bfraw* __restrict__ WT, const float* __restrict__ bcat,
    bfraw* __restrict__ valueOut, bfraw* __restrict__ proj, int M,
    int ibf, int qbf)
{
  __shared__ bfraw As[128][40];   // [m][k], +8 pad
  __shared__ bfraw Bs[128][40];   // [n][k]
  const int y = blockIdx.y;
  const void* Araw; const bfraw* Abf; int wtb, colb, bmode, abf;
  if (y < 2) { Araw = inflat; Abf = inflatB; abf = ibf;
               wtb = y * 128;             colb = y * 128;       bmode = 1; }
  else       { Araw = query;  Abf = queryB;  abf = qbf;
               wtb = 256 + (y - 2) * 128; colb = (y - 2) * 128; bmode = 0; }
  const int f32m = abf ? 0 : vote_f32(query);

  const int bm = blockIdx.x * 128;
  const int tid = threadIdx.x;
  const int wave = tid >> 6, lane = tid & 63;
  const int quad = lane >> 4, l16 = lane & 15;
  const int mb = (wave >> 1) * 64, nb = (wave & 1) * 64;
  const int srow = tid >> 1;
  const int sk = (tid & 1) * 16;

  int lr = bm + srow; if (lr >= M) lr = M - 1;
  const size_t aoff = (size_t)lr * 256;

  f32x4 acc[4][4] = {{{0.f}}};

  for (int k0 = 0; k0 < 256; k0 += 32) {
    uint4 pa0, pa1;
    if (abf) {
      const bfraw* Ab = Abf + aoff + (k0 + sk);
      pa0 = ((const uint4*)Ab)[0];
      pa1 = ((const uint4*)Ab)[1];
    } else if (f32m) {
      const float* Af = (const float*)Araw + aoff + (k0 + sk);
      const float4 x0 = ((const float4*)Af)[0];
      const float4 x1 = ((const float4*)Af)[1];
      const float4 x2 = ((const float4*)Af)[2];
      const float4 x3 = ((const float4*)Af)[3];
      pa0.x = pk2(x0.x, x0.y); pa0.y = pk2(x0.z, x0.w);
      pa0.z = pk2(x1.x, x1.y); pa0.w = pk2(x1.z, x1.w);
      pa1.x = pk2(x2.x, x2.y); pa1.y = pk2(x2.z, x2.w);
      pa1.z = pk2(x3.x, x3.y); pa1.w = pk2(x3.z, x3.w);
    } else {
      const bfraw* Ab = (const bfraw*)Araw + aoff + (k0 + sk);
      pa0 = ((const uint4*)Ab)[0];
      pa1 = ((const uint4*)Ab)[1];
    }
    const bfraw* Bb = WT + (size_t)(wtb + srow) * 256 + (k0 + sk);
    const uint4 pb0 = ((const uint4*)Bb)[0];
    const uint4 pb1 = ((const uint4*)Bb)[1];
    *(uint4*)&As[srow][sk]     = pa0;
    *(uint4*)&As[srow][sk + 8] = pa1;
    *(uint4*)&Bs[srow][sk]     = pb0;
    *(uint4*)&Bs[srow][sk + 8] = pb1;
    __syncthreads();

    bf16x8 af[4], bf[4];
#pragma unroll
    for (int i = 0; i < 4; ++i)
      af[i] = *(const bf16x8*)&As[mb + i * 16 + l16][quad * 8];
#pragma unroll
    for (int j = 0; j < 4; ++j)
      bf[j] = *(const bf16x8*)&Bs[nb + j * 16 + l16][quad * 8];
#pragma unroll
    for (int i = 0; i < 4; ++i)
#pragma unroll
      for (int j = 0; j < 4; ++j)
        acc[i][j] = __builtin_amdgcn_mfma_f32_16x16x32_bf16(af[i], bf[j], acc[i][j], 0, 0, 0);
    __syncthreads();
  }

#pragma unroll
  for (int j = 0; j < 4; ++j) {
    const int col = colb + nb + j * 16 + l16;
    const float bb = bmode ? bcat[768 + col] : bcat[col];
#pragma unroll
    for (int i = 0; i < 4; ++i) {
#pragma unroll
      for (int r = 0; r < 4; ++r) {
        const int lrow = bm + mb + i * 16 + quad * 4 + r;
        if (lrow < M) {
          const float vv = acc[i][j][r] + bb;
          if (!bmode)
            proj[(size_t)lrow * 768 + col] = f2bf(vv);
          else
            valueOut[((unsigned)(col >> 5) * (unsigned)M + (unsigned)lrow) * 32u
                     + (unsigned)(col & 31)] = f2bf(vv);
        }
      }
    }
  }
}

// O-projection GEMM: out[0..M) = core @ W_o + b_o; core = proj rows cols[0,256)
// (bf16, stride 768, written by sampler overlay). C dtype per vote; b_o from
// bcat[1024..1280).
__global__ __launch_bounds__(256) void gemmO_k(
    const bfraw* __restrict__ proj, const bfraw* __restrict__ WT,
    const float* __restrict__ bcat, void* __restrict__ Cout,
    const void* __restrict__ query, int M)
{
  __shared__ bfraw As[128][40];
  __shared__ bfraw Bs[128][40];
  const int f32m = vote_f32(query);
  const int bm = blockIdx.x * 128;
  const int bn = blockIdx.y * 128;
  const int tid = threadIdx.x;
  const int wave = tid >> 6, lane = tid & 63;
  const int quad = lane >> 4, l16 = lane & 15;
  const int mb = (wave >> 1) * 64, nb = (wave & 1) * 64;
  const int srow = tid >> 1;
  const int sk = (tid & 1) * 16;

  int lr = bm + srow; if (lr >= M) lr = M - 1;
  const size_t aoff = (size_t)lr * 768;

  f32x4 acc[4][4] = {{{0.f}}};

  for (int k0 = 0; k0 < 256; k0 += 32) {
    const bfraw* Ab = proj + aoff + (k0 + sk);
    const uint4 pa0 = ((const uint4*)Ab)[0];
    const uint4 pa1 = ((const uint4*)Ab)[1];
    const bfraw* Bb = WT + (size_t)(1024 + bn + srow) * 256 + (k0 + sk);
    const uint4 pb0 = ((const uint4*)Bb)[0];
    const uint4 pb1 = ((const uint4*)Bb)[1];
    *(uint4*)&As[srow][sk]     = pa0;
    *(uint4*)&As[srow][sk + 8] = pa1;
    *(uint4*)&Bs[srow][sk]     = pb0;
    *(uint4*)&Bs[srow][sk + 8] = pb1;
    __syncthreads();

    bf16x8 af[4], bf[4];
#pragma unroll
    for (int i = 0; i < 4; ++i)
      af[i] = *(const bf16x8*)&As[mb + i * 16 + l16][quad * 8];
#pragma unroll
    for (int j = 0; j < 4; ++j)
      bf[j] = *(const bf16x8*)&Bs[nb + j * 16 + l16][quad * 8];
#pragma unroll
    for (int i = 0; i < 4; ++i)
#pragma unroll
      for (int j = 0; j < 4; ++j)
        acc[i][j] = __builtin_amdgcn_mfma_f32_16x16x32_bf16(af[i], bf[j], acc[i][j], 0, 0, 0);
    __syncthreads();
  }

#pragma unroll
  for (int j = 0; j < 4; ++j) {
    const int col = bn + nb + j * 16 + l16;
    const float bb = bcat[1024 + col];
#pragma unroll
    for (int i = 0; i < 4; ++i) {
#pragma unroll
      for (int r = 0; r < 4; ++r) {
        const int lrow = bm + mb + i * 16 + quad * 4 + r;
        if (lrow < M) {
          const float v = acc[i][j][r] + bb;
          if (f32m) ((float*)Cout)[(size_t)lrow * 256 + col] = v;
          else      ((bfraw*)Cout)[(size_t)lrow * 256 + col] = f2bf(v);
        }
      }
    }
  }
}

// Sampler, head-major: grid (2040, 8); block = 8 q x 1 h. bf16 head-major
// value [NH][16320][32] (1.04MB/head live set, 64B/pixel = one line).
// Voteless; refp/toff pre-converted f32. 32-bit gather addressing.
// R15: no min-occupancy clamp; 16 gathers issued as named regs (2x8 batch)
// BEFORE consumption; float2-packed consume (v_pk_fma_f32 opportunity).
__global__ __launch_bounds__(256) void sampler_k(
    bfraw* __restrict__ proj, const bfraw* __restrict__ value,
    const float* __restrict__ refp, const float* __restrict__ toff)
{
  __shared__ __align__(16) int   s_idx[256][4];  // clamped pixel index
  __shared__ __align__(16) float s_w[256][4];    // attn*bilinear, 0 if OOB

  const int h = blockIdx.y;
  const int tid = threadIdx.x;
  const int qi = tid >> 5;         // query-in-block 0..7
  const int sp = tid & 31;         // point-in-head
  const int l = sp >> 3;           // level
  const int p = sp & 7;            // 0..3 current, 4..7 temporal
  const int qg = blockIdx.x * 8 + qi;

  const int W_i[4]  = {64, 32, 16, 8};
  const int TH_i[4] = {192, 96, 48, 24};
  const int ST_i[4] = {0, 12288, 15360, 16128};
  const float Wf  = (float)W_i[l];
  const float THf = (float)TH_i[l];

  bfraw* prow = proj + (size_t)qg * 768;

  // ---- joint softmax over 32 logits of (qg, h) — shfl in 32-lane group ----
  const float logit = (p < 4) ? bf2f(prow[512 + h * 16 + l * 4 + p])
                              : bf2f(prow[640 + h * 16 + l * 4 + (p - 4)]);
  float mx = logit;
#pragma unroll
  for (int m = 16; m >= 1; m >>= 1) mx = fmaxf(mx, __shfl_xor(mx, m));
  const float e = __expf(logit - mx);
  float ssum = e;
#pragma unroll
  for (int m = 16; m >= 1; m >>= 1) ssum += __shfl_xor(ssum, m);
  const float attn = e / ssum;

  // ---- sampling location + bilinear corner descriptors ----
  const float rx = refp[(unsigned)(qg * 4 + l) * 2 + 0];
  const float ry = refp[(unsigned)(qg * 4 + l) * 2 + 1];
  float ox, oy;
  if (p < 4) {
    ox = bf2f(prow[h * 32 + l * 8 + p * 2 + 0]) / Wf;
    oy = bf2f(prow[h * 32 + l * 8 + p * 2 + 1]) / THf;
  } else {
    const int pj = p - 4, tw = pj >> 1, j = pj & 1;
    ox = toff[(unsigned)(qg * 4 + l) * 4 + tw * 2 + 0] +
         bf2f(prow[256 + h * 32 + l * 8 + tw * 4 + j * 2 + 0]) / Wf;
    oy = toff[(unsigned)(qg * 4 + l) * 4 + tw * 2 + 1] +
         bf2f(prow[256 + h * 32 + l * 8 + tw * 4 + j * 2 + 1]) / THf;
  }
  const float x = (rx + ox) * Wf - 0.5f;   // grid_sample align_corners=False
  const float y = (ry + oy) * THf - 0.5f;
  const float x0f = floorf(x), y0f = floorf(y);
  const float lx = x - x0f, ly = y - y0f;
  const int x0 = (int)x0f, y0 = (int)y0f;
  const int Wg = W_i[l], THg = TH_i[l], ST = ST_i[l];
  const float cwx[2] = {1.f - lx, lx};
  const float cwy[2] = {1.f - ly, ly};
#pragma unroll
  for (int c = 0; c < 4; ++c) {
    const int xi = x0 + (c & 1), yi = y0 + (c >> 1);
    const bool inb = (xi >= 0) & (xi < Wg) & (yi >= 0) & (yi < THg);
    const int xc = min(max(xi, 0), Wg - 1);
    const int yc = min(max(yi, 0), THg - 1);
    s_idx[tid][c] = ST + yc * Wg + xc;
    s_w[tid][c] = inb ? (attn * cwx[c & 1] * cwy[c >> 1]) : 0.f;
  }
  __syncthreads();

  // ---- gather: thread = (qi, pt-group pg 0..7, ch-quad chq 0..3) ----
  {
    const int pg = sp >> 2;
    const int chq = sp & 3;
    const char* vb = (const char*)(value + (unsigned)h * (16320u * 32u));
    const unsigned cb = (unsigned)(chq << 4);
    int   idx[16];
    float ww[16];
#pragma unroll
    for (int pt = 0; pt < 4; ++pt) {
      const int ds = qi * 32 + pg * 4 + pt;
      const int4   ia = *(const int4*)&s_idx[ds][0];    // ds_read_b128
      const float4 wa = *(const float4*)&s_w[ds][0];    // ds_read_b128
      idx[pt * 4 + 0] = ia.x; idx[pt * 4 + 1] = ia.y;
      idx[pt * 4 + 2] = ia.z; idx[pt * 4 + 3] = ia.w;
      ww[pt * 4 + 0] = wa.x; ww[pt * 4 + 1] = wa.y;
      ww[pt * 4 + 2] = wa.z; ww[pt * 4 + 3] = wa.w;
    }
#define GLD(n) const uint4 v##n = *(const uint4*)(vb + ((((unsigned)idx[n]) << 6) | cb))
    // batch 1: 8 loads issued back-to-back (no consumer between)
    GLD(0); GLD(1); GLD(2); GLD(3); GLD(4); GLD(5); GLD(6); GLD(7);
    // batch 2: 8 more — all 16 in flight before first consume
    GLD(8); GLD(9); GLD(10); GLD(11); GLD(12); GLD(13); GLD(14); GLD(15);
#undef GLD
    f32x2 a0 = {0.f, 0.f}, a1 = {0.f, 0.f}, a2 = {0.f, 0.f}, a3 = {0.f, 0.f};
#define CONS(n) {                                            \
    const float w = ww[n];                                   \
    const f32x2 w2 = {w, w};                                 \
    f32x2 t;                                                 \
    t.x = lo16f(v##n.x); t.y = hi16f(v##n.x); a0 += w2 * t;  \
    t.x = lo16f(v##n.y); t.y = hi16f(v##n.y); a1 += w2 * t;  \
    t.x = lo16f(v##n.z); t.y = hi16f(v##n.z); a2 += w2 * t;  \
    t.x = lo16f(v##n.w); t.y = hi16f(v##n.w); a3 += w2 * t;  }
    CONS(0); CONS(1); CONS(2); CONS(3); CONS(4); CONS(5); CONS(6); CONS(7);
    CONS(8); CONS(9); CONS(10); CONS(11); CONS(12); CONS(13); CONS(14); CONS(15);
#undef CONS
    float acc[8] = {a0.x, a0.y, a1.x, a1.y, a2.x, a2.y, a3.x, a3.y};
    // reduce over pg (lane bits 2..4 — stays within the 32-lane group)
#pragma unroll
    for (int m = 4; m <= 16; m <<= 1)
#pragma unroll
      for (int r = 0; r < 8; ++r)
        acc[r] += __shfl_xor(acc[r], m);
    if (pg == 0) {   // core overlay: prow[h*32 + chq*8 .. +8) := slice (bf16)
      uint4 pk;
      pk.x = pk2(acc[0], acc[1]);
      pk.y = pk2(acc[2], acc[3]);
      pk.z = pk2(acc[4], acc[5]);
      pk.w = pk2(acc[6], acc[7]);
      *(uint4*)(prow + h * 32 + chq * 8) = pk;
    }
  }
}

extern "C" void kernel_launch(void* const* d_in, const int* in_sizes, int n_in,
                              void* d_out, int out_size, void* d_ws, size_t ws_size,
                              hipStream_t stream)
{
  const void* query  = d_in[0];
  const void* refp   = d_in[1];
  const void* toff   = d_in[2];
  const void* inflat = d_in[3];
  const void* W_so  = d_in[6];
  const void* b_so  = d_in[7];
  const void* W_tso = d_in[8];
  const void* b_tso = d_in[9];
  const void* W_aw  = d_in[10];
  const void* b_aw  = d_in[11];
  const void* W_taw = d_in[12];
  const void* b_taw = d_in[13];
  const void* W_v   = d_in[14];
  const void* b_v   = d_in[15];
  const void* W_o   = d_in[16];
  const void* b_o   = d_in[17];

  const int Lq = 16320;
  // ws layout: WT bf16[1280][256] | bcat f32[1280] | refpF f32[130560] |
  //   toffF f32[261120] | value bf16 [8][Lq][32] | proj bf16 [Lq][768] |
  //   queryB bf16 [Lq][256] | inflatB bf16 [Lq][256]
  const size_t WT_B   = (size_t)1280 * 256 * 2;     //    655,360
  const size_t BCAT_B = 1280 * 4;                   //      5,120
  const size_t REFP_B = (size_t)Lq * 8 * 4;         //    522,240
  const size_t TOFF_B = (size_t)Lq * 16 * 4;        //  1,044,480
  const size_t VAL_B  = (size_t)8 * Lq * 32 * 2;    //  8,355,840
  const size_t PROJ_B = (size_t)Lq * 768 * 2;       // 25,067,520
  const size_t QB_B   = (size_t)Lq * 256 * 2;       //  8,355,840
  const size_t base   = WT_B + BCAT_B + REFP_B + TOFF_B + VAL_B + PROJ_B; // 35,650,560

  const int qbf = (ws_size >= base + QB_B)     ? 1 : 0;  // 44,006,400 (R12-proven tier)
  const int ibf = (ws_size >= base + 2 * QB_B) ? 1 : 0;  // 52,362,240

  char* wp = (char*)d_ws;
  bfraw* WT     = (bfraw*)wp; wp += WT_B;
  float* bcat   = (float*)wp; wp += BCAT_B;
  float* refpF  = (float*)wp; wp += REFP_B;
  float* toffF  = (float*)wp; wp += TOFF_B;
  bfraw* value  = (bfraw*)wp; wp += VAL_B;
  bfraw* proj   = (bfraw*)wp; wp += PROJ_B;
  bfraw* queryB = (bfraw*)wp; wp += QB_B;   // valid only if qbf
  bfraw* inflatB= (bfraw*)wp;               // valid only if ibf

  const dim3 blk(256);
  const int prep_blocks = ibf ? 6895 : (qbf ? 4855 : 2815);
  prep_k<<<dim3(prep_blocks), blk, 0, stream>>>(
      W_v, W_so, W_tso, W_aw, W_taw, W_o,
      b_so, b_tso, b_aw, b_taw, b_v, b_o,
      refp, toff, query, inflat,
      WT, bcat, refpF, toffF, queryB, inflatB, qbf, ibf);
  gemmVP_k<<<dim3(128, 8), blk, 0, stream>>>(inflat, query, inflatB, queryB,
                                             WT, bcat, value, proj, Lq, ibf, qbf);
  sampler_k<<<dim3(Lq / 8, 8), blk, 0, stream>>>(proj, value, refpF, toffF);
  gemmO_k<<<dim3(128, 2), blk, 0, stream>>>(proj, WT, bcat, d_out, query, Lq);
}